// Round 7
// baseline (4749.369 us; speedup 1.0000x reference)
//
#include <hip/hip_runtime.h>

// LangModelWithLSTM on MI355X (gfx950). fp32 inputs, fp32 output.
// embed-concat -> [xg GEMM -> persistent biLSTM recurrence] x2 -> MLP head.
// fp32 accuracy via bf16 MFMA with hi/lo splitting:
//   GEMMs: K-tripled streams  A={a_hi,a_lo,a_hi} x B={w_hi,w_hi,w_lo}
//   recurrence: (h_hi + h_lo) x W_hi   (W_lo term negligible)
// Cross-WG h exchange v8 = v5 sentinel protocol + v3's in-wave gate mapping:
//   - per-step unique buffers (no ring, no ABA): slot g = dir*512 + step,
//     each 32KB = {hi[16][512], lo[16][512]} bf16 planes, pre-filled 0x7F
//     (u32 0x7F7F7F7F = impossible bf16 for |h|<1). Producer: relaxed AGENT
//     u32 stores, no flag/barrier. Consumer: staging thread polls ITS 16 u64
//     until no u32 == sentinel -> ds_write_b64. One MALL RT on the chain.
//   - wave owns ALL 4 gates for its 8 units (tile0=i/f, tile1=g/o); gate
//     halves exchanged with __shfl_xor(8), unit pairs with __shfl_xor(1);
//     pointwise duplicated across lane pairs. NO gx LDS, NO second barrier.
//     ONE __syncthreads/step (staging -> ds_read). Each wave publishes as
//     soon as its own MFMA+pointwise completes (no slowest-wave skew).
//   - hs overwrite safety without B2: stage(s+1) happens-after poll(s+1)
//     happens-after every wave's publish(s+1), data-dependent on its
//     ds_reads(s) -> no laggard-reader hazard.
// B=16, S=512, H=512, D_IN=1024, 4H=2048, HID=1024, C=5, L=2 bidirectional.

typedef unsigned short u16;
typedef unsigned int   u32;
typedef unsigned long long u64;
typedef short s16x8 __attribute__((ext_vector_type(8)));   // MFMA A/B frag (8 bf16)
typedef float f32x4 __attribute__((ext_vector_type(4)));   // MFMA accumulator

#define SENT32 0x7F7F7F7Fu

__device__ __forceinline__ float b2f(u16 h) { return __uint_as_float(((u32)h) << 16); }
__device__ __forceinline__ u16 f2b(float x) {            // round-to-nearest-even
  u32 u = __float_as_uint(x);
  return (u16)((u + 0x7fffu + ((u >> 16) & 1u)) >> 16);
}
// A-side pair -> 3 u32 words: u16 stream {h0,l0,h0, h1,l1,h1}
__device__ __forceinline__ void packA3(float v0, float v1, u32& w0, u32& w1, u32& w2) {
  u16 h0 = f2b(v0), h1 = f2b(v1);
  u16 l0 = f2b(v0 - b2f(h0)), l1 = f2b(v1 - b2f(h1));
  w0 = (u32)h0 | ((u32)l0 << 16);
  w1 = (u32)h0 | ((u32)h1 << 16);
  w2 = (u32)l1 | ((u32)h1 << 16);
}
// B-side pair -> 3 u32 words: u16 stream {h0,h0,l0, h1,h1,l1}
__device__ __forceinline__ void packB3(float v0, float v1, u32& w0, u32& w1, u32& w2) {
  u16 h0 = f2b(v0), h1 = f2b(v1);
  u16 l0 = f2b(v0 - b2f(h0)), l1 = f2b(v1 - b2f(h1));
  w0 = (u32)h0 | ((u32)h0 << 16);
  w1 = (u32)l0 | ((u32)h1 << 16);
  w2 = (u32)h1 | ((u32)l1 << 16);
}

// ---------------------------------------------------------------- embed -> A3 triple
__global__ __launch_bounds__(256) void k_embed(const int* __restrict__ x,
    const float* __restrict__ lang, const float* __restrict__ emb, u16* __restrict__ A3) {
  const int m = blockIdx.x;                  // 8192 rows = b*512+s
  const int k = threadIdx.x * 4;             // 4 source elems
  const float* src = (k < 768) ? (lang + (size_t)m * 768 + k)
                               : (emb + (size_t)x[m] * 256 + (k - 768));
  float4 v = *(const float4*)src;
  u32 w0, w1, w2, w3, w4, w5;
  packA3(v.x, v.y, w0, w1, w2);
  packA3(v.z, v.w, w3, w4, w5);
  uint2* dst = (uint2*)(A3 + (size_t)m * 3072 + 3 * k);
  dst[0] = make_uint2(w0, w1); dst[1] = make_uint2(w2, w3); dst[2] = make_uint2(w4, w5);
}

// ---------------------------------------------------------------- weight preps
// fp32 W [rows][1024] -> triple [rows][3072]; one quad per thread.
__global__ __launch_bounds__(256) void k_prepw(const float* __restrict__ W,
    u16* __restrict__ W3, int nq) {
  const int idx = blockIdx.x * 256 + threadIdx.x;
  if (idx >= nq) return;
  const int base = idx * 4, row = base >> 10, k = base & 1023;
  float4 v = *(const float4*)(W + base);
  u32 w0, w1, w2, w3, w4, w5;
  packB3(v.x, v.y, w0, w1, w2);
  packB3(v.z, v.w, w3, w4, w5);
  uint2* dst = (uint2*)(W3 + (size_t)row * 3072 + 3 * k);
  dst[0] = make_uint2(w0, w1); dst[1] = make_uint2(w2, w3); dst[2] = make_uint2(w4, w5);
}
// Whh fp32 flat [4194304] -> hi bf16 plane (lo plane dropped in recurrence)
__global__ __launch_bounds__(256) void k_prepwh(const float* __restrict__ W,
    u16* __restrict__ hi) {
  const int idx = blockIdx.x * 256 + threadIdx.x;   // 1,048,576 quads
  const int base = idx * 4;
  float4 v = *(const float4*)(W + base);
  float vv[4] = {v.x, v.y, v.z, v.w};
  u16 h[4];
#pragma unroll
  for (int i = 0; i < 4; ++i) h[i] = f2b(vv[i]);
  *(uint2*)(hi + base) = make_uint2((u32)h[0] | ((u32)h[1] << 16), (u32)h[2] | ((u32)h[3] << 16));
}
__global__ __launch_bounds__(256) void k_prepb(const float* __restrict__ bih,
    const float* __restrict__ bhh, float* __restrict__ bsum) {
  const int tid = blockIdx.x * 256 + threadIdx.x;   // 8192
  bsum[tid] = bih[tid] + bhh[tid];
}
// act fp32 [8192][1024] -> A3 triple
__global__ __launch_bounds__(256) void k_tri(const float* __restrict__ act, u16* __restrict__ A3) {
  const int idx = blockIdx.x * 256 + threadIdx.x;   // 2,097,152 quads
  const int base = idx * 4, row = base >> 10, k = base & 1023;
  float4 v = *(const float4*)(act + base);
  u32 w0, w1, w2, w3, w4, w5;
  packA3(v.x, v.y, w0, w1, w2);
  packA3(v.z, v.w, w3, w4, w5);
  uint2* dst = (uint2*)(A3 + (size_t)row * 3072 + 3 * k);
  dst[0] = make_uint2(w0, w1); dst[1] = make_uint2(w2, w3); dst[2] = make_uint2(w4, w5);
}

// ---------------------------------------------------------------- GEMM (m97 style)
// C[m][n] = sum_k A[m][k]*B[n][k] + bias[n]. 128x128 tile, BK=32, 4 waves.
// EPI=0: fp32 -> xg layout [dir=n>>11][(s*16+b)][n&2047]  (N==4096)
// EPI=1: fp32 [m][N] + leaky-relu -> act.
template <int EPI>
__global__ __launch_bounds__(256) void k_gemm(const u16* __restrict__ A,
    const u16* __restrict__ B, const float* __restrict__ bias, float* __restrict__ outp,
    int Ka, int N) {
  __shared__ u16 As[4096];   // [128][32]
  __shared__ u16 Bs[4096];
  const int tid = threadIdx.x, wave = tid >> 6, lane = tid & 63;
  const int bm0 = blockIdx.x * 128, bn0 = blockIdx.y * 128;
  const int wm = (wave & 1) * 64, wn = (wave >> 1) * 64;
  const int kq = (lane >> 4) * 8;
  f32x4 acc[4][4];
#pragma unroll
  for (int i = 0; i < 4; ++i)
#pragma unroll
    for (int j = 0; j < 4; ++j) acc[i][j] = (f32x4){0.f, 0.f, 0.f, 0.f};

  const int srow = tid >> 2, soff = (tid & 3) * 8;
  const u16* Ag  = A + (size_t)(bm0 + srow) * Ka + soff;
  const u16* Ag2 = Ag + (size_t)64 * Ka;
  const u16* Bg  = B + (size_t)(bn0 + srow) * Ka + soff;
  const u16* Bg2 = Bg + (size_t)64 * Ka;
  u16* sA = As + wave * 512;
  u16* sB = Bs + wave * 512;

  for (int k0 = 0; k0 < Ka; k0 += 32) {
    __syncthreads();
    __builtin_amdgcn_global_load_lds((const __attribute__((address_space(1))) void*)(Ag + k0),
        (__attribute__((address_space(3))) void*)sA, 16, 0, 0);
    __builtin_amdgcn_global_load_lds((const __attribute__((address_space(1))) void*)(Ag2 + k0),
        (__attribute__((address_space(3))) void*)(sA + 2048), 16, 0, 0);
    __builtin_amdgcn_global_load_lds((const __attribute__((address_space(1))) void*)(Bg + k0),
        (__attribute__((address_space(3))) void*)sB, 16, 0, 0);
    __builtin_amdgcn_global_load_lds((const __attribute__((address_space(1))) void*)(Bg2 + k0),
        (__attribute__((address_space(3))) void*)(sB + 2048), 16, 0, 0);
    __syncthreads();
    s16x8 af[4], bf[4];
#pragma unroll
    for (int mi = 0; mi < 4; ++mi) af[mi] = *(const s16x8*)(As + (wm + mi * 16 + (lane & 15)) * 32 + kq);
#pragma unroll
    for (int ni = 0; ni < 4; ++ni) bf[ni] = *(const s16x8*)(Bs + (wn + ni * 16 + (lane & 15)) * 32 + kq);
#pragma unroll
    for (int mi = 0; mi < 4; ++mi)
#pragma unroll
      for (int ni = 0; ni < 4; ++ni)
        acc[mi][ni] = __builtin_amdgcn_mfma_f32_16x16x32_bf16(af[mi], bf[ni], acc[mi][ni], 0, 0, 0);
  }

#pragma unroll
  for (int mi = 0; mi < 4; ++mi)
#pragma unroll
    for (int r = 0; r < 4; ++r) {
      const int m = bm0 + wm + mi * 16 + (lane >> 4) * 4 + r;
#pragma unroll
      for (int ni = 0; ni < 4; ++ni) {
        const int n = bn0 + wn + ni * 16 + (lane & 15);
        float v = acc[mi][ni][r] + bias[n];
        if (EPI == 0) {
          const size_t off = (size_t)(n >> 11) * 16777216u
                           + (size_t)((m & 511) * 16 + (m >> 9)) * 2048 + (n & 2047);
          outp[off] = v;
        } else {
          v = (v > 0.f) ? v : 0.01f * v;
          outp[(size_t)m * N + n] = v;
        }
      }
    }
}

// ---------------------------------------------------------------- persistent biLSTM v8
// 32 WGs: dir = blk>>4; WG owns 32 hidden units; wave owns 8 units x ALL 4
// gates (tile0 cols: gate i (half0) | gate f (half1); tile1: g | o). After
// MFMA, lane pairs (col, col^8) swap gate halves via shfl_xor(8), unit pairs
// via shfl_xor(1); pointwise duplicated. Publish by st-lanes (half==0, even
// u7): hi/lo u32 per (batch, unit-pair). Sentinel slots + poll as v5.
__global__ __launch_bounds__(256, 1) void k_rec(const float* __restrict__ xg,
    const u16* __restrict__ WhiP, const int* __restrict__ lens, u16* __restrict__ Yt,
    u16* __restrict__ stepA, u16* __restrict__ stepB) {
  __shared__ u16 hs[2 * 16 * 520];     // [plane hi/lo][batch][512+8 pad]
  const int tid = threadIdx.x, wave = tid >> 6, lane = tid & 63;
  const int dir = blockIdx.x >> 4, slice = blockIdx.x & 15, ubase = slice * 32;
  const int col = lane & 15, grp = lane >> 4;
  const int bq = grp * 4, kq = grp * 8;
  const int half = col >> 3, u7 = col & 7;
  const int ug = ubase + wave * 8 + u7;           // global unit in [0,512)

  // B fragments: tile j covers gate (2*j + half), unit ug
  s16x8 bfrag[2][16];
#pragma unroll
  for (int j = 0; j < 2; ++j) {
    const u16* wr = WhiP + ((size_t)dir * 2048 + (size_t)(2 * j + half) * 512 + ug) * 512 + kq;
#pragma unroll
    for (int kt = 0; kt < 16; ++kt) bfrag[j][kt] = *(const s16x8*)(wr + kt * 32);
  }
  int lenv[4];
#pragma unroll
  for (int r = 0; r < 4; ++r) lenv[r] = lens[bq + r];
  float c_[4] = {0.f, 0.f, 0.f, 0.f}, h_[4] = {0.f, 0.f, 0.f, 0.f};
  const float* xgp = xg + (size_t)dir * 16777216u;
  // staging thread coords: plane sp, batch row srow, 64B-interleaved chunk soff
  const int sp = tid >> 7, srow = (tid & 127) >> 3, soff = tid & 7;
  const int cg0 = half * 512 + ug;                // xg col, tile0 (gates i/f)
  const int cg1 = cg0 + 1024;                     // tile1 (gates g/o)
  const bool st = (half == 0) && ((u7 & 1) == 0); // storing lane (even unit, half 0)

  for (int s = 0; s < 512; ++s) {
    const int t = dir ? (511 - s) : s;
    // xg prefetch (in flight during poll); C rows = batches bq+r
    const float* xr = xgp + ((size_t)t * 16 + bq) * 2048;
    f32x4 a0, a1;
#pragma unroll
    for (int r = 0; r < 4; ++r) { a0[r] = xr[r * 2048 + cg0]; a1[r] = xr[r * 2048 + cg1]; }

    if (s > 0) {
      // poll slot g = dir*512 + s : sentinel data-as-flag (v5 protocol)
      const int g = dir * 512 + s;
      const u64* slot64 = (const u64*)((g < 768) ? (stepA + (size_t)g * 16384)
                                                 : (stepB + (size_t)(g - 768) * 16384));
      const u64* src = slot64 + sp * 2048 + srow * 128 + soff;
      u64 wv[16];
      bool ok;
      do {
#pragma unroll
        for (int i = 0; i < 16; ++i)
          wv[i] = __hip_atomic_load(src + i * 8, __ATOMIC_RELAXED, __HIP_MEMORY_SCOPE_AGENT);
        ok = true;
#pragma unroll
        for (int i = 0; i < 16; ++i)
          ok &= ((u32)wv[i] != SENT32) & ((u32)(wv[i] >> 32) != SENT32);
      } while (!ok);
      u64* drow = (u64*)(hs + sp * 8320 + srow * 520);
#pragma unroll
      for (int i = 0; i < 16; ++i) drow[soff + i * 8] = wv[i];
    }
    __syncthreads();                     // B1: staging -> ds_read (only barrier)
    if (s > 0) {
      f32x4 l0 = (f32x4){0.f, 0.f, 0.f, 0.f}, l1 = (f32x4){0.f, 0.f, 0.f, 0.f};
      const u16* hh = hs + col * 520 + kq;     // A row = batch = col
      const u16* hl = hh + 8320;
#pragma unroll
      for (int kt = 0; kt < 16; ++kt) {
        s16x8 ah = *(const s16x8*)(hh + kt * 32);
        s16x8 al = *(const s16x8*)(hl + kt * 32);
        a0 = __builtin_amdgcn_mfma_f32_16x16x32_bf16(ah, bfrag[0][kt], a0, 0, 0, 0);
        a1 = __builtin_amdgcn_mfma_f32_16x16x32_bf16(ah, bfrag[1][kt], a1, 0, 0, 0);
        l0 = __builtin_amdgcn_mfma_f32_16x16x32_bf16(al, bfrag[0][kt], l0, 0, 0, 0);
        l1 = __builtin_amdgcn_mfma_f32_16x16x32_bf16(al, bfrag[1][kt], l1, 0, 0, 0);
      }
      a0 += l0; a1 += l1;
    }

    // in-wave gate exchange + pointwise (duplicated across lane pairs col<->col^8)
    float yh[4], ynb[4];
    u32 hiw[4], low[4];
#pragma unroll
    for (int r = 0; r < 4; ++r) {
      const float oth0 = __shfl_xor(a0[r], 8, 64);
      const float oth1 = __shfl_xor(a1[r], 8, 64);
      const float gi = half ? oth0 : a0[r];
      const float gf = half ? a0[r] : oth0;
      const float gg = half ? oth1 : a1[r];
      const float go = half ? a1[r] : oth1;
      const float ii = 1.f / (1.f + __expf(-gi));
      const float ff = 1.f / (1.f + __expf(-gf));
      const float gz = 1.f - 2.f / (__expf(2.f * gg) + 1.f);   // tanh
      const float oo = 1.f / (1.f + __expf(-go));
      const float cn = ff * c_[r] + ii * gz;
      const float hn = oo * (1.f - 2.f / (__expf(2.f * cn) + 1.f));
      const bool mk = (t < lenv[r]);
      c_[r] = mk ? cn : c_[r];
      h_[r] = mk ? hn : h_[r];
      yh[r] = mk ? hn : 0.f;
    }
#pragma unroll
    for (int r = 0; r < 4; ++r) {                  // pair units (ug, ug+1)
      const float hb = __shfl_xor(h_[r], 1, 64);
      const u16 mh = f2b(h_[r]), nh = f2b(hb);
      const u16 ml = f2b(h_[r] - b2f(mh)), nl = f2b(hb - b2f(nh));
      hiw[r] = (u32)mh | ((u32)nh << 16);
      low[r] = (u32)ml | ((u32)nl << 16);
      ynb[r] = __shfl_xor(yh[r], 1, 64);
    }
    if (s < 511 && st) {                 // publish carried h to slot g+1 (hi/lo planes)
      const int gw = dir * 512 + s + 1;
      u16* slot = (gw < 768) ? (stepA + (size_t)gw * 16384)
                             : (stepB + (size_t)(gw - 768) * 16384);
#pragma unroll
      for (int r = 0; r < 4; ++r) {
        u32* dh = (u32*)(slot + (size_t)(bq + r) * 512 + ug);          // hi plane
        u32* dl = (u32*)(slot + 8192 + (size_t)(bq + r) * 512 + ug);   // lo plane
        __hip_atomic_store(dh, hiw[r], __ATOMIC_RELAXED, __HIP_MEMORY_SCOPE_AGENT);
        __hip_atomic_store(dl, low[r], __ATOMIC_RELAXED, __HIP_MEMORY_SCOPE_AGENT);
      }
    }
    __builtin_amdgcn_sched_barrier(0);   // keep Yt stores after the publish
    if (st) {                            // next-layer A-triple output
#pragma unroll
      for (int r = 0; r < 4; ++r) {
        u32 w0, w1, w2;
        packA3(yh[r], ynb[r], w0, w1, w2);
        u32* yp = (u32*)(Yt + (size_t)((bq + r) * 512 + t) * 3072
                         + 3 * (size_t)(dir * 512 + ug));
        yp[0] = w0; yp[1] = w1; yp[2] = w2;
      }
    }
  }
}

// ---------------------------------------------------------------- head: out = a2 @ W3^T + b3
__global__ __launch_bounds__(256) void k_head(const float* __restrict__ a2,
    const float* __restrict__ W3, const float* __restrict__ b3, float* __restrict__ out) {
  const int m = (blockIdx.x * 256 + threadIdx.x) >> 6;   // wave per row
  const int lane = threadIdx.x & 63;
  const float* row = a2 + (size_t)m * 1024;
  float s[5] = {0.f, 0.f, 0.f, 0.f, 0.f};
  for (int j = lane; j < 1024; j += 64) {
    const float v = row[j];
#pragma unroll
    for (int c = 0; c < 5; ++c) s[c] += v * W3[c * 1024 + j];
  }
#pragma unroll
  for (int c = 0; c < 5; ++c)
    for (int off = 32; off > 0; off >>= 1) s[c] += __shfl_down(s[c], off, 64);
  if (lane == 0)
#pragma unroll
    for (int c = 0; c < 5; ++c) out[(size_t)m * 5 + c] = s[c] + b3[c];   // fp32 output
}

// ---------------------------------------------------------------- launch
extern "C" void kernel_launch(void* const* d_in, const int* in_sizes, int n_in,
                              void* d_out, int out_size, void* d_ws, size_t ws_size,
                              hipStream_t stream) {
  const int*   x    = (const int*)d_in[0];
  const int*   lens = (const int*)d_in[1];
  const float* lang = (const float*)d_in[2];
  const float* emb  = (const float*)d_in[3];
  const float* Wih  = (const float*)d_in[4];   // [2][2][2048][1024]
  const float* Whh  = (const float*)d_in[5];   // [2][2][2048][512]
  const float* bih  = (const float*)d_in[6];
  const float* bhh  = (const float*)d_in[7];
  const float* W1   = (const float*)d_in[8];
  const float* b1   = (const float*)d_in[9];
  const float* W2   = (const float*)d_in[10];
  const float* b2   = (const float*)d_in[11];
  const float* W3   = (const float*)d_in[12];
  const float* b3   = (const float*)d_in[13];
  float* out = (float*)d_out;
  char* ws = (char*)d_ws;

  // workspace (~223 MiB). act overlays xg (xg dead after k_rec layer 1).
  // stepA overlays wb3 (wb3 dead during k_rec); stepB is the 8.39MB hole.
  float* xg     = (float*)(ws + 0);             // [2][8192][2048] f32  134,217,728
  float* act    = (float*)(ws + 0);             //  [8192][1024] f32 overlay
  u16*   A3     = (u16*)(ws + 134217728);       //  [8192][3072] u16     50,331,648
  u16*   wb3    = (u16*)(ws + 184549376);       //  [4096][3072] u16     25,165,824
  u16*   stepA  = (u16*)(ws + 184549376);       //  768 slots x 32KB overlay of wb3
  u16*   whh_hi = (u16*)(ws + 209715200);       //  [2][2][2048][512]     8,388,608
  u16*   stepB  = (u16*)(ws + 218103808);       //  256 slots x 32KB      8,388,608
  u16*   w3b    = (u16*)(ws + 226492416);       //  [1024][3072] u16      6,291,456
  float* bsum   = (float*)(ws + 233046016);     //  [2][2][2048]             32,768

  k_prepb<<<32, 256, 0, stream>>>(bih, bhh, bsum);
  k_prepwh<<<4096, 256, 0, stream>>>(Whh, whh_hi);
  k_embed<<<8192, 256, 0, stream>>>(x, lang, emb, A3);

  // layer 0
  k_prepw<<<4096, 256, 0, stream>>>(Wih, wb3, 1048576);
  k_gemm<0><<<dim3(64, 32), 256, 0, stream>>>(A3, wb3, bsum, xg, 3072, 4096);
  hipMemsetAsync(stepA, 0x7F, 25165824, stream);   // sentinel-fill (wb3 dead now)
  hipMemsetAsync(stepB, 0x7F, 8388608, stream);
  k_rec<<<32, 256, 0, stream>>>(xg, whh_hi, lens, A3, stepA, stepB);
  // layer 1
  k_prepw<<<4096, 256, 0, stream>>>(Wih + 4194304, wb3, 1048576);
  k_gemm<0><<<dim3(64, 32), 256, 0, stream>>>(A3, wb3, bsum + 4096, xg, 3072, 4096);
  hipMemsetAsync(stepA, 0x7F, 25165824, stream);
  hipMemsetAsync(stepB, 0x7F, 8388608, stream);
  k_rec<<<32, 256, 0, stream>>>(xg, whh_hi + 2097152, lens, A3, stepA, stepB);
  // head
  k_prepw<<<1024, 256, 0, stream>>>(W1, w3b, 262144);
  k_gemm<1><<<dim3(64, 8), 256, 0, stream>>>(A3, w3b, b1, act, 3072, 1024);
  k_tri<<<8192, 256, 0, stream>>>(act, A3);
  k_prepw<<<1024, 256, 0, stream>>>(W2, w3b, 262144);
  k_gemm<1><<<dim3(64, 8), 256, 0, stream>>>(A3, w3b, b2, act, 3072, 1024);
  k_head<<<2048, 256, 0, stream>>>(act, W3, b3, out);
}